// Round 1
// baseline (912.603 us; speedup 1.0000x reference)
//
#include <hip/hip_runtime.h>
#include <hip/hip_bf16.h>

typedef __bf16 bf16_t;
typedef __bf16 bf16x8 __attribute__((ext_vector_type(8)));
typedef float  f32x4  __attribute__((ext_vector_type(4)));

#define NNROWS 65536

__device__ __forceinline__ void g2l16(const void* g, void* l) {
  __builtin_amdgcn_global_load_lds(
      (const __attribute__((address_space(1))) void*)g,
      (__attribute__((address_space(3))) void*)l, 16, 0, 0);
}

// ---- P2: cemb f32 -> bf16 ----
__global__ __launch_bounds__(256) void k_cvt_cemb(const float* __restrict__ src,
                                                  bf16_t* __restrict__ dst) {
  size_t i = ((size_t)blockIdx.x * 256 + threadIdx.x) * 8;
  float4 t0 = *(const float4*)(src + i);
  float4 t1 = *(const float4*)(src + i + 4);
  bf16x8 v;
  v[0] = (bf16_t)t0.x; v[1] = (bf16_t)t0.y; v[2] = (bf16_t)t0.z; v[3] = (bf16_t)t0.w;
  v[4] = (bf16_t)t1.x; v[5] = (bf16_t)t1.y; v[6] = (bf16_t)t1.z; v[7] = (bf16_t)t1.w;
  *(bf16x8*)(dst + i) = v;
}

// ---- P1: W1cT[n][k] = W1[2048+k][n] (bf16) ----
__global__ __launch_bounds__(256) void k_w1ct(const float* __restrict__ W1,
                                              bf16_t* __restrict__ W1cT) {
  __shared__ float ls[64][65];
  int t = threadIdx.x;
  int kt = blockIdx.x & 3, nt = blockIdx.x >> 2;
  #pragma unroll
  for (int q = 0; q < 16; ++q) {
    int idx = q * 256 + t, r = idx >> 6, c = idx & 63;
    ls[r][c] = W1[(size_t)(2048 + kt * 64 + r) * 1024 + nt * 64 + c];
  }
  __syncthreads();
  #pragma unroll
  for (int q = 0; q < 16; ++q) {
    int idx = q * 256 + t, nr = idx >> 6, kc = idx & 63;
    W1cT[(size_t)(nt * 64 + nr) * 256 + kt * 64 + kc] = (bf16_t)ls[kc][nr];
  }
}

// ---- P3: hi = feats@W1[:1024] + b1 ; hj = feats@W1[1024:2048] (f32) ----
__global__ __launch_bounds__(256) void k_hihj(const float* __restrict__ feats,
                                              const float* __restrict__ W1,
                                              const float* __restrict__ b1,
                                              float* __restrict__ hi,
                                              float* __restrict__ hj) {
  __shared__ float fs[4][1024];
  int t = threadIdx.x;
  int z = blockIdx.x & 1, ig = blockIdx.x >> 1;  // 64 groups of 4 rows
  #pragma unroll
  for (int q = 0; q < 16; ++q) {
    int idx = q * 256 + t, r = idx >> 10, c = idx & 1023;
    fs[r][c] = feats[(size_t)(ig * 4 + r) * 1024 + c];
  }
  __syncthreads();
  float acc[4][4] = {};
  const float* Wz = W1 + (size_t)z * 1024 * 1024;
  for (int k = 0; k < 1024; ++k) {
    float w0 = Wz[(size_t)k * 1024 + t];
    float w1v = Wz[(size_t)k * 1024 + 256 + t];
    float w2v = Wz[(size_t)k * 1024 + 512 + t];
    float w3v = Wz[(size_t)k * 1024 + 768 + t];
    #pragma unroll
    for (int r = 0; r < 4; ++r) {
      float f = fs[r][k];
      acc[r][0] += f * w0; acc[r][1] += f * w1v;
      acc[r][2] += f * w2v; acc[r][3] += f * w3v;
    }
  }
  float* out = z ? hj : hi;
  #pragma unroll
  for (int r = 0; r < 4; ++r)
    #pragma unroll
    for (int q = 0; q < 4; ++q) {
      int n = q * 256 + t;
      float v = acc[r][q];
      if (z == 0) v += b1[n];
      out[(size_t)(ig * 4 + r) * 1024 + n] = v;
    }
}

// ---- P4: WrelT[n][k] = W_rel[k][n], n padded to 64 with zeros ----
__global__ __launch_bounds__(256) void k_wrelt(const float* __restrict__ Wrel,
                                               bf16_t* __restrict__ WrelT) {
  int n = blockIdx.x;  // 0..63
  int t = threadIdx.x;
  for (int k = t; k < 1024; k += 256) {
    float v = (n < 51) ? Wrel[(size_t)k * 51 + n] : 0.f;
    WrelT[(size_t)n * 1024 + k] = (bf16_t)v;
  }
}

// ---- K1: pass A — h = leaky(cemb@W1c + hi + hj + b1), bf16 out + BN stats ----
__global__ __launch_bounds__(256) void k_passA(const bf16_t* __restrict__ Ab,
                                               const bf16_t* __restrict__ Bt,
                                               const float* __restrict__ hi_b1,
                                               const float* __restrict__ hj,
                                               bf16_t* __restrict__ hout,
                                               float* __restrict__ stats) {
  __shared__ bf16_t lsA[128 * 32];
  __shared__ bf16_t lsB[128 * 32];
  const int t = threadIdx.x, lane = t & 63, wid = t >> 6;
  const int wm = wid >> 1, wn = wid & 1;
  int bid = blockIdx.x;
  int swz = (bid & 7) * 512 + (bid >> 3);   // XCD-chunked, bijective (4096 % 8 == 0)
  const int bn = swz & 7, bm = swz >> 3;

  const char* gA = (const char*)Ab + (size_t)(bm * 128 + (t >> 2)) * 512 + (t & 3) * 16;
  const char* gB = (const char*)Bt + (size_t)(bn * 128 + (t >> 2)) * 512 + (t & 3) * 16;
  char* lA0 = (char*)lsA + wid * 1024;
  char* lB0 = (char*)lsB + wid * 1024;

  f32x4 acc[4][4];
  #pragma unroll
  for (int a = 0; a < 4; ++a)
    #pragma unroll
    for (int b = 0; b < 4; ++b)
      #pragma unroll
      for (int e = 0; e < 4; ++e) acc[a][b][e] = 0.f;

  for (int kt = 0; kt < 8; ++kt) {
    if (kt) __syncthreads();
    size_t ko = (size_t)kt * 64;
    g2l16(gA + ko, lA0);
    g2l16(gA + ko + (size_t)64 * 512, lA0 + 4096);
    g2l16(gB + ko, lB0);
    g2l16(gB + ko + (size_t)64 * 512, lB0 + 4096);
    __syncthreads();
    const char* pa = (const char*)lsA + (wm * 64 + (lane & 15)) * 64 + (lane >> 4) * 16;
    const char* pb = (const char*)lsB + (wn * 64 + (lane & 15)) * 64 + (lane >> 4) * 16;
    bf16x8 af[4], bfr[4];
    #pragma unroll
    for (int mf = 0; mf < 4; ++mf) af[mf] = *(const bf16x8*)(pa + mf * 1024);
    #pragma unroll
    for (int nf = 0; nf < 4; ++nf) bfr[nf] = *(const bf16x8*)(pb + nf * 1024);
    #pragma unroll
    for (int mf = 0; mf < 4; ++mf)
      #pragma unroll
      for (int nf = 0; nf < 4; ++nf)
        acc[mf][nf] = __builtin_amdgcn_mfma_f32_16x16x32_bf16(af[mf], bfr[nf], acc[mf][nf], 0, 0, 0);
  }

  const int colbase = bn * 128 + wn * 64 + (lane & 15);
  const int i_blk = bm >> 1;  // i is uniform per block (128 rows = half a j-sweep)
  float hiv[4];
  #pragma unroll
  for (int nf = 0; nf < 4; ++nf) hiv[nf] = hi_b1[(size_t)i_blk * 1024 + colbase + nf * 16];
  float ssum[4] = {0.f, 0.f, 0.f, 0.f}, sq[4] = {0.f, 0.f, 0.f, 0.f};
  #pragma unroll
  for (int mf = 0; mf < 4; ++mf) {
    #pragma unroll
    for (int rg = 0; rg < 4; ++rg) {
      int rl = wm * 64 + mf * 16 + ((lane >> 4) << 2) + rg;
      const float* hjr = hj + (size_t)((bm & 1) * 128 + rl) * 1024;
      bf16_t* ho = hout + (size_t)(bm * 128 + rl) * 1024;
      #pragma unroll
      for (int nf = 0; nf < 4; ++nf) {
        int c = colbase + nf * 16;
        float v = acc[mf][nf][rg] + hiv[nf] + hjr[c];
        v = v >= 0.f ? v : 0.01f * v;
        ho[c] = (bf16_t)v;
        ssum[nf] += v;
        sq[nf] += v * v;
      }
    }
  }
  #pragma unroll
  for (int nf = 0; nf < 4; ++nf) {
    float s = ssum[nf], q = sq[nf];
    s += __shfl_xor(s, 16); q += __shfl_xor(q, 16);
    s += __shfl_xor(s, 32); q += __shfl_xor(q, 32);
    if ((lane >> 4) == 0) {
      atomicAdd(&stats[colbase + nf * 16], s);
      atomicAdd(&stats[1024 + colbase + nf * 16], q);
    }
  }
}

// ---- K2a: finalize BN stats -> a,c ; init b2p ----
__global__ void k_stats(const float* __restrict__ gamma, const float* __restrict__ beta,
                        const float* __restrict__ b2, const float* __restrict__ stats,
                        float* __restrict__ ab, float* __restrict__ b2p) {
  int k = blockIdx.x * 256 + threadIdx.x;
  float s = stats[k], q = stats[1024 + k];
  float mean = s * (1.f / 65536.f);
  float var = q * (1.f / 65536.f) - mean * mean;
  float a = gamma[k] * rsqrtf(var + 1e-5f);
  float c = beta[k] - mean * a;
  ab[k] = a;
  ab[1024 + k] = c;
  b2p[k] = b2[k];
}

// ---- K2b: W2pT[n][k] = a[k]*W2[k][n] (bf16); b2p[n] += sum_k c[k]*W2[k][n] ----
__global__ __launch_bounds__(256) void k_w2pt(const float* __restrict__ W2,
                                              const float* __restrict__ ab,
                                              bf16_t* __restrict__ W2pT,
                                              float* __restrict__ b2p) {
  __shared__ float ls[64][65];
  __shared__ float red[256];
  int t = threadIdx.x;
  int kt = blockIdx.x & 15, nt = blockIdx.x >> 4;
  float cpart = 0.f;
  #pragma unroll
  for (int q = 0; q < 16; ++q) {
    int idx = q * 256 + t, r = idx >> 6, c = idx & 63;
    float v = W2[(size_t)(kt * 64 + r) * 1024 + nt * 64 + c];
    ls[r][c] = v;
    cpart += ab[1024 + kt * 64 + r] * v;   // c[k] * W2[k][n], n fixed per thread
  }
  __syncthreads();
  #pragma unroll
  for (int q = 0; q < 16; ++q) {
    int idx = q * 256 + t, nr = idx >> 6, kc = idx & 63;
    W2pT[(size_t)(nt * 64 + nr) * 1024 + kt * 64 + kc] = (bf16_t)(ab[kt * 64 + kc] * ls[kc][nr]);
  }
  red[t] = cpart;
  __syncthreads();
  if (t < 64) {
    float s2 = red[t] + red[t + 64] + red[t + 128] + red[t + 192];
    atomicAdd(&b2p[nt * 64 + t], s2);
  }
}

// ---- K3: pass B — feat = h@W2' + b2' (f32 out) + fused conf partials ----
__global__ __launch_bounds__(256) void k_passB(const bf16_t* __restrict__ hb,
                                               const bf16_t* __restrict__ W2pT,
                                               const float* __restrict__ b2p,
                                               const float* __restrict__ watt,
                                               float* __restrict__ feat,
                                               float* __restrict__ conf) {
  __shared__ bf16_t lsA[128 * 32];
  __shared__ bf16_t lsB[128 * 32];
  const int t = threadIdx.x, lane = t & 63, wid = t >> 6;
  const int wm = wid >> 1, wn = wid & 1;
  int bid = blockIdx.x;
  int swz = (bid & 7) * 512 + (bid >> 3);
  const int bn = swz & 7, bm = swz >> 3;

  const char* gA = (const char*)hb + (size_t)(bm * 128 + (t >> 2)) * 2048 + (t & 3) * 16;
  const char* gB = (const char*)W2pT + (size_t)(bn * 128 + (t >> 2)) * 2048 + (t & 3) * 16;
  char* lA0 = (char*)lsA + wid * 1024;
  char* lB0 = (char*)lsB + wid * 1024;

  f32x4 acc[4][4];
  #pragma unroll
  for (int a = 0; a < 4; ++a)
    #pragma unroll
    for (int b = 0; b < 4; ++b)
      #pragma unroll
      for (int e = 0; e < 4; ++e) acc[a][b][e] = 0.f;

  for (int kt = 0; kt < 32; ++kt) {
    if (kt) __syncthreads();
    size_t ko = (size_t)kt * 64;
    g2l16(gA + ko, lA0);
    g2l16(gA + ko + (size_t)64 * 2048, lA0 + 4096);
    g2l16(gB + ko, lB0);
    g2l16(gB + ko + (size_t)64 * 2048, lB0 + 4096);
    __syncthreads();
    const char* pa = (const char*)lsA + (wm * 64 + (lane & 15)) * 64 + (lane >> 4) * 16;
    const char* pb = (const char*)lsB + (wn * 64 + (lane & 15)) * 64 + (lane >> 4) * 16;
    bf16x8 af[4], bfr[4];
    #pragma unroll
    for (int mf = 0; mf < 4; ++mf) af[mf] = *(const bf16x8*)(pa + mf * 1024);
    #pragma unroll
    for (int nf = 0; nf < 4; ++nf) bfr[nf] = *(const bf16x8*)(pb + nf * 1024);
    #pragma unroll
    for (int mf = 0; mf < 4; ++mf)
      #pragma unroll
      for (int nf = 0; nf < 4; ++nf)
        acc[mf][nf] = __builtin_amdgcn_mfma_f32_16x16x32_bf16(af[mf], bfr[nf], acc[mf][nf], 0, 0, 0);
  }

  const int colbase = bn * 128 + wn * 64 + (lane & 15);
  const int rowb = bm * 128 + wm * 64 + ((lane >> 4) << 2);
  float b2v[4], wav[4];
  #pragma unroll
  for (int nf = 0; nf < 4; ++nf) {
    int c = colbase + nf * 16;
    b2v[nf] = b2p[c];
    wav[nf] = watt[c];
  }
  #pragma unroll
  for (int mf = 0; mf < 4; ++mf) {
    #pragma unroll
    for (int rg = 0; rg < 4; ++rg) {
      int r = rowb + mf * 16 + rg;
      float* fr = feat + (size_t)r * 1024;
      float cp = 0.f;
      #pragma unroll
      for (int nf = 0; nf < 4; ++nf) {
        float v = acc[mf][nf][rg] + b2v[nf];
        fr[colbase + nf * 16] = v;
        cp += v * wav[nf];
      }
      cp += __shfl_xor(cp, 1); cp += __shfl_xor(cp, 2);
      cp += __shfl_xor(cp, 4); cp += __shfl_xor(cp, 8);
      if ((lane & 15) == 0) atomicAdd(&conf[r], cp);
    }
  }
}

// ---- K4: row softmax over j (b_att shift-invariant, omitted) ----
__global__ __launch_bounds__(256) void k_softmax(float* __restrict__ conf) {
  __shared__ float red[8];
  int i = blockIdx.x, t = threadIdx.x;
  float x = conf[i * 256 + t];
  float m = x;
  #pragma unroll
  for (int d = 1; d < 64; d <<= 1) m = fmaxf(m, __shfl_xor(m, d));
  if ((t & 63) == 0) red[t >> 6] = m;
  __syncthreads();
  m = fmaxf(fmaxf(red[0], red[1]), fmaxf(red[2], red[3]));
  float e = __expf(x - m);
  float s = e;
  #pragma unroll
  for (int d = 1; d < 64; d <<= 1) s += __shfl_xor(s, d);
  if ((t & 63) == 0) red[4 + (t >> 6)] = s;
  __syncthreads();
  s = red[4] + red[5] + red[6] + red[7];
  conf[i * 256 + t] = e / s;
}

// ---- K5: enhanced[i,o] = sum_j conf[i,j]*feat[i,j,o] ----
__global__ __launch_bounds__(256) void k_enh(const float* __restrict__ feat,
                                             const float* __restrict__ conf,
                                             float* __restrict__ out) {
  __shared__ float cw[256];
  int bid = blockIdx.x, i = bid >> 2, oc = bid & 3;
  int t = threadIdx.x;
  cw[t] = conf[i * 256 + t];
  __syncthreads();
  const float* fp = feat + (size_t)i * 256 * 1024 + oc * 256 + t;
  float a = 0.f;
  #pragma unroll 4
  for (int j = 0; j < 256; ++j) a += cw[j] * fp[(size_t)j * 1024];
  out[(size_t)i * 1024 + oc * 256 + t] = a;
}

// ---- K6: relation = feat@W_rel + b_rel (MFMA, f32 A converted on the fly) ----
__global__ __launch_bounds__(256) void k_rel(const float* __restrict__ feat,
                                             const bf16_t* __restrict__ WrelT,
                                             const float* __restrict__ brel,
                                             float* __restrict__ out) {
  const int t = threadIdx.x, lane = t & 63, w = t >> 6;
  const int r0 = blockIdx.x * 64 + w * 16;
  const float* ap = feat + (size_t)(r0 + (lane & 15)) * 1024 + ((lane >> 4) << 3);
  const bf16_t* bp = WrelT + (size_t)(lane & 15) * 1024 + ((lane >> 4) << 3);
  f32x4 acc[4];
  #pragma unroll
  for (int nf = 0; nf < 4; ++nf)
    #pragma unroll
    for (int e = 0; e < 4; ++e) acc[nf][e] = 0.f;
  for (int kt = 0; kt < 32; ++kt) {
    float4 t0 = *(const float4*)(ap + kt * 32);
    float4 t1 = *(const float4*)(ap + kt * 32 + 4);
    bf16x8 af;
    af[0] = (bf16_t)t0.x; af[1] = (bf16_t)t0.y; af[2] = (bf16_t)t0.z; af[3] = (bf16_t)t0.w;
    af[4] = (bf16_t)t1.x; af[5] = (bf16_t)t1.y; af[6] = (bf16_t)t1.z; af[7] = (bf16_t)t1.w;
    #pragma unroll
    for (int nf = 0; nf < 4; ++nf) {
      bf16x8 bfr = *(const bf16x8*)(bp + (size_t)nf * 16 * 1024 + kt * 32);
      acc[nf] = __builtin_amdgcn_mfma_f32_16x16x32_bf16(af, bfr, acc[nf], 0, 0, 0);
    }
  }
  #pragma unroll
  for (int nf = 0; nf < 4; ++nf) {
    int c = nf * 16 + (lane & 15);
    if (c < 51) {
      float bb = brel[c];
      #pragma unroll
      for (int rg = 0; rg < 4; ++rg) {
        int rr = r0 + ((lane >> 4) << 2) + rg;
        out[(size_t)rr * 51 + c] = acc[nf][rg] + bb;
      }
    }
  }
}

extern "C" void kernel_launch(void* const* d_in, const int* in_sizes, int n_in,
                              void* d_out, int out_size, void* d_ws, size_t ws_size,
                              hipStream_t stream) {
  const float* feats = (const float*)d_in[0];
  const float* cemb  = (const float*)d_in[1];
  const float* W1    = (const float*)d_in[2];
  const float* b1    = (const float*)d_in[3];
  const float* gamma = (const float*)d_in[4];
  const float* beta  = (const float*)d_in[5];
  const float* W2    = (const float*)d_in[6];
  const float* b2    = (const float*)d_in[7];
  const float* watt  = (const float*)d_in[8];
  // d_in[9] = b_att: softmax is shift-invariant -> unused
  const float* Wrel  = (const float*)d_in[10];
  const float* brel  = (const float*)d_in[11];

  float* feat = (float*)d_out;                       // [65536][1024]
  float* enh  = (float*)d_out + (size_t)67108864;    // [256][1024]
  float* rel  = (float*)d_out + (size_t)67371008;    // [65536][51]

  char* ws = (char*)d_ws;
  bf16_t* h     = (bf16_t*)(ws + 0);                 // 134217728 B
  bf16_t* cembb = (bf16_t*)(ws + 134217728);         //  33554432 B
  bf16_t* W1cT  = (bf16_t*)(ws + 167772160);         //    524288 B
  bf16_t* W2pT  = (bf16_t*)(ws + 168296448);         //   2097152 B
  bf16_t* WrelT = (bf16_t*)(ws + 170393600);         //    131072 B
  float*  hi    = (float*)(ws + 170524672);          //   1048576 B
  float*  hj    = (float*)(ws + 171573248);          //   1048576 B
  float*  stats = (float*)(ws + 172621824);          //      8192 B
  float*  ab    = (float*)(ws + 172630016);          //      8192 B
  float*  b2p   = (float*)(ws + 172638208);          //      4096 B
  float*  conf  = (float*)(ws + 172642304);          //    262144 B

  hipMemsetAsync(stats, 0, 2 * 1024 * sizeof(float), stream);
  hipMemsetAsync(conf, 0, (size_t)65536 * sizeof(float), stream);

  k_cvt_cemb<<<8192, 256, 0, stream>>>(cemb, cembb);
  k_w1ct<<<64, 256, 0, stream>>>(W1, W1cT);
  k_hihj<<<128, 256, 0, stream>>>(feats, W1, b1, hi, hj);
  k_wrelt<<<64, 256, 0, stream>>>(Wrel, WrelT);
  k_passA<<<4096, 256, 0, stream>>>(cembb, W1cT, hi, hj, h, stats);
  k_stats<<<4, 256, 0, stream>>>(gamma, beta, b2, stats, ab, b2p);
  k_w2pt<<<256, 256, 0, stream>>>(W2, ab, W2pT, b2p);
  k_passB<<<4096, 256, 0, stream>>>(h, W2pT, b2p, watt, feat, conf);
  k_softmax<<<256, 256, 0, stream>>>(conf);
  k_enh<<<1024, 256, 0, stream>>>(feat, conf, enh);
  k_rel<<<1024, 256, 0, stream>>>(feat, WrelT, brel, rel);
}